// Round 12
// baseline (454.473 us; speedup 1.0000x reference)
//
#include <hip/hip_runtime.h>

// Problem constants
#define B_N 4096
#define T_N 512
// Output layout (floats): final (B,T,2) | fwd_out (B,2) | noise (B,T,1)
#define FWD_OFF   (B_N * T_N * 2)        // 4194304
#define NOISE_OFF (FWD_OFF + B_N * 2)    // 4202496

#define S_SIG  (-1.4426950408889634f)   // -log2(e)
#define S_TANH (-2.8853900817779268f)   // -2*log2(e)

typedef float v2f __attribute__((ext_vector_type(2)));
typedef unsigned int uv2 __attribute__((ext_vector_type(2)));
__device__ __forceinline__ v2f mkv2(float a, float b) { v2f r; r.x = a; r.y = b; return r; }

// native packed math: clang selects v_pk_fma_f32 / v_pk_mul_f32 (gfx90a+)
__device__ __forceinline__ v2f pk_fma(v2f a, v2f b, v2f c) { return a * b + c; }

// act on pre-scaled accumulator: returns fma(A, rcp(1+exp2(a)), B)
// A=1,B=0  -> sigmoid(v) where a = -log2e*v
// A=2,B=-1 -> tanh(v)    where a = -2log2e*v
__device__ __forceinline__ float act_ab(float a, float A, float Bc) {
    float r = __builtin_amdgcn_rcpf(1.0f + __builtin_amdgcn_exp2f(a));
    return fmaf(A, r, Bc);
}
__device__ __forceinline__ float sig_acc(float a) {
    return __builtin_amdgcn_rcpf(1.0f + __builtin_amdgcn_exp2f(a));
}
__device__ __forceinline__ float tanh_nat(float v) {
    return fmaf(2.0f, __builtin_amdgcn_rcpf(1.0f + __builtin_amdgcn_exp2f(v * S_TANH)), -1.0f);
}

// ---- all-VALU cross-lane (zero DS in the kernel) ----
// ROW_ROR:N (0x120+N): dst lane i <- src lane (i-N)&15 within each 16-lane row
// ROW_NEWBCAST:J (0x150+J): dst lane i <- src lane J of its own 16-lane row
template<int CTRL>
__device__ __forceinline__ float dppf(float v) {
    return __int_as_float(__builtin_amdgcn_update_dpp(
        __float_as_int(v), __float_as_int(v), CTRL, 0xF, 0xF, false));
}
// permlane16_swap (HW-validated in round 3): rows {r0,r1,r2,r3} ->
//   ev = {r0,r0,r2,r2} (even-row value on both rows of each 32-half)
//   od = {r1,r1,r3,r3} (odd-row value on both rows)
// Element-safe for 32-lane element groups (rows 0,1 vs 2,3 never mix).
__device__ __forceinline__ void pl16(float v, float& ev, float& od) {
    uv2 q = __builtin_amdgcn_permlane16_swap(
        __float_as_uint(v), __float_as_uint(v), false, false);
    ev = __uint_as_float(q.x);
    od = __uint_as_float(q.y);
}

// Round-12: 32 lanes/elem (2 elems/wave) -> 2048 waves = 2 waves/SIMD, to fill
// the 24% chain-stall idle that placement changes (round 11) could not touch.
// Round-2's validated algorithm (layer-pipelined encoder: L0 rows on row0,
// L1 rows on row1; gate-split decoder: {i,f} row0, {g,o} row1) with ALL
// cross-lane via DPP + permlane16_swap (round-1/2's spill and DS-latency
// failure modes removed). waves_per_eu(2,2) pins the 2-wave VGPR budget.
__global__ __attribute__((amdgpu_waves_per_eu(2, 2))) __launch_bounds__(256)
void fused_kernel(
    const float* __restrict__ x,
    const float* __restrict__ eWih0, const float* __restrict__ eWhh0,
    const float* __restrict__ ebih0, const float* __restrict__ ebhh0,
    const float* __restrict__ eWih1, const float* __restrict__ eWhh1,
    const float* __restrict__ ebih1, const float* __restrict__ ebhh1,
    const float* __restrict__ dWih0, const float* __restrict__ dWhh0,
    const float* __restrict__ dbih0, const float* __restrict__ dbhh0,
    const float* __restrict__ dWih1, const float* __restrict__ dWhh1,
    const float* __restrict__ dbih1, const float* __restrict__ dbhh1,
    const float* __restrict__ fcW, const float* __restrict__ fcb,
    const float* __restrict__ outW, const float* __restrict__ outb,
    float* __restrict__ out)
{
    const int tid = blockIdx.x * 256 + threadIdx.x;
    const int b   = tid >> 5;          // batch element (32 lanes each)
    const int l   = tid & 31;          // lane within element group
    const int r16 = l & 15;            // position within 16-lane row
    const int gg  = l >> 4;            // row parity: 0 = even row, 1 = odd row

    // =================== ENCODER (H=4), layer-pipelined ===================
    // row0 (gg=0): the 16 L0 gate rows; row1 (gg=1): the 16 L1 gate rows.
    // L1 runs in lockstep on the SAME step as L0 consumes x(t) - i.e. L1(t)
    // uses h0(t) broadcast within the same body (round-2 validated dataflow).
    const int kk = r16 >> 2;
    const float sc = (kk == 2) ? S_TANH : S_SIG;
    const float Ak = (kk == 2) ? 2.0f : 1.0f;
    const float Bk = (kk == 2) ? -1.0f : 0.0f;

    v2f h0f[2], h1p[2];
    float c0all, c1all;
    float fw0, fw1;

    {
        const float* whsrc = gg ? eWhh1 : eWhh0;            // self-layer h weights
        const float wx = gg ? 0.0f : eWih0[r16] * sc;       // x weight (L0 only)
        const float eb = ((gg ? ebih1[r16] : ebih0[r16]) +
                          (gg ? ebhh1[r16] : ebhh0[r16])) * sc;
        v2f whp[2], wip[2];
#pragma unroll
        for (int j = 0; j < 2; ++j) {
            whp[j] = mkv2(whsrc[r16 * 4 + 2 * j], whsrc[r16 * 4 + 2 * j + 1]) * sc;
            wip[j] = gg ? mkv2(eWih1[r16 * 4 + 2 * j], eWih1[r16 * 4 + 2 * j + 1]) * sc
                        : mkv2(0.f, 0.f);
        }

        // vp = own-layer h (row0: h0, row1: h1); wq = h0 on both rows
        v2f vp[2] = {mkv2(0.f, 0.f), mkv2(0.f, 0.f)};
        v2f wq[2] = {mkv2(0.f, 0.f), mkv2(0.f, 0.f)};
        float c = 0.f, hu = 0.f;

        auto ebody = [&](float xc) {
            v2f acc = pk_fma(whp[0], vp[0], mkv2(fmaf(wx, xc, eb), 0.f));
            acc = pk_fma(whp[1], vp[1], acc);
            acc = pk_fma(wip[0], wq[0], acc);     // L1: Wih1 . h0(prev body); L0: 0
            acc = pk_fma(wip[1], wq[1], acc);
            float gate = act_ab(acc.x + acc.y, Ak, Bk);
            // gate combine within each row (src lane = (i-N)&15):
            // on lanes 0..3: ror:12 -> i+4 (f), ror:8 -> i+8 (g), ror:4 -> i+12 (o)
            float fv = dppf<0x12C>(gate);
            float gv = dppf<0x128>(gate);
            float ov = dppf<0x124>(gate);
            c = fmaf(fv, c, gate * gv);           // valid on lanes 0..3 of each row
            hu = ov * tanh_nat(c);
            // own-layer h broadcast (within own row)
            vp[0].x = dppf<0x150>(hu); vp[0].y = dppf<0x151>(hu);
            vp[1].x = dppf<0x152>(hu); vp[1].y = dppf<0x153>(hu);
            // h0 (even-row hu) to BOTH rows, then broadcast within rows
            float h0all, dum;
            pl16(hu, h0all, dum);
            wq[0].x = dppf<0x150>(h0all); wq[0].y = dppf<0x151>(h0all);
            wq[1].x = dppf<0x152>(h0all); wq[1].y = dppf<0x153>(h0all);
        };

        const float4* __restrict__ xq4 = (const float4*)(x + (long)b * T_N);
        float4 xq = xq4[0];
        float4 xn = xq4[1];

        ebody(xq.x);                              // s=0: L0 -> h0(0); L1 ran bogus
        if (gg) {                                 // neutralize L1's bogus first step
            c = 0.f; vp[0] = mkv2(0.f, 0.f); vp[1] = mkv2(0.f, 0.f);
        }
        ebody(xq.y); ebody(xq.z); ebody(xq.w);    // s=1..3
        xq = xn;
#pragma unroll 1
        for (int tb = 1; tb < T_N / 4; ++tb) {    // s=4..511
            xn = (tb + 1 < T_N / 4) ? xq4[tb + 1] : xq;  // prefetch
            ebody(xq.x); ebody(xq.y); ebody(xq.z); ebody(xq.w);
            xq = xn;
        }
        // After 512 bodies: L0 at h0(511) (in wq), c row0 = c0(511).
        // L1 is at h1(510): save handoff, one more body for h1(511)/c1(511).
        h0f[0] = wq[0]; h0f[1] = wq[1];
        const float c0sav = c;
        ebody(0.f);                               // only the L1 row meaningful

        // h1(511) uniform: odd-row hu to both rows, then row broadcasts
        float he, ho;
        pl16(hu, he, ho);
        h1p[0].x = dppf<0x150>(ho); h1p[0].y = dppf<0x151>(ho);
        h1p[1].x = dppf<0x152>(ho); h1p[1].y = dppf<0x153>(ho);
        // cell handoff: positional (lane r16 holds unit r16's cell, both rows)
        float ce, co;
        pl16(c0sav, ce, co); c0all = ce;          // c0[r16], valid r16<4
        pl16(c, ce, co);     c1all = co;          // c1[r16], valid r16<4
    }

    // fwd_out = h1 @ fc_W.T + fc_b (uniform on all lanes)
    fw0 = fcb[0];
    fw1 = fcb[1];
    fw0 = fmaf(fcW[0], h1p[0].x, fw0); fw0 = fmaf(fcW[1], h1p[0].y, fw0);
    fw0 = fmaf(fcW[2], h1p[1].x, fw0); fw0 = fmaf(fcW[3], h1p[1].y, fw0);
    fw1 = fmaf(fcW[4], h1p[0].x, fw1); fw1 = fmaf(fcW[5], h1p[0].y, fw1);
    fw1 = fmaf(fcW[6], h1p[1].x, fw1); fw1 = fmaf(fcW[7], h1p[1].y, fw1);
    if (l == 0) {
        out[FWD_OFF + b * 2 + 0] = fw0;
        out[FWD_OFF + b * 2 + 1] = fw1;
    }

    __builtin_amdgcn_sched_barrier(0);  // keep decoder weight loads out of the encoder

    // =================== DECODER (H=10), gate-split ===================
    // row0 computes gates {i(0), f(1)} of unit u = r16; row1 computes {g(2), o(3)}.
    // Units 10..15 shadow unit 9 (never read back). Both rows then hold all four
    // gate values via 2 permlane16_swap and compute cells redundantly (uniform).
    const int u  = r16;
    const int uc = (u < 10) ? u : 9;
    const int r0 = (gg * 2 + 0) * 10 + uc;         // slot a row (i or g)
    const int r1 = (gg * 2 + 1) * 10 + uc;         // slot b row (f or o)
    const float sc0 = gg ? S_TANH : S_SIG;         // slot a: tanh iff g-gate
    const float A0v = gg ? 2.0f : 1.0f;
    const float B0v = gg ? -1.0f : 0.0f;

    const float wih0a = dWih0[r0] * sc0;
    const float wih0b = dWih0[r1] * S_SIG;
    const float b0a = (dbih0[r0] + dbhh0[r0]) * sc0;
    const float b0b = (dbih0[r1] + dbhh0[r1]) * S_SIG;
    const float b1a = (dbih1[r0] + dbhh1[r0]) * sc0;
    const float b1b = (dbih1[r1] + dbhh1[r1]) * S_SIG;

    v2f whh0a[5], whh0b[5], wih1a[5], wih1b[5], whh1a[5], whh1b[5];
#pragma unroll
    for (int j = 0; j < 5; ++j) {
        whh0a[j] = mkv2(dWhh0[r0 * 10 + 2 * j], dWhh0[r0 * 10 + 2 * j + 1]) * sc0;
        whh0b[j] = mkv2(dWhh0[r1 * 10 + 2 * j], dWhh0[r1 * 10 + 2 * j + 1]) * S_SIG;
        wih1a[j] = mkv2(dWih1[r0 * 10 + 2 * j], dWih1[r0 * 10 + 2 * j + 1]) * sc0;
        wih1b[j] = mkv2(dWih1[r1 * 10 + 2 * j], dWih1[r1 * 10 + 2 * j + 1]) * S_SIG;
        whh1a[j] = mkv2(dWhh1[r0 * 10 + 2 * j], dWhh1[r0 * 10 + 2 * j + 1]) * sc0;
        whh1b[j] = mkv2(dWhh1[r1 * 10 + 2 * j], dWhh1[r1 * 10 + 2 * j + 1]) * S_SIG;
    }
    v2f outwp[5];
#pragma unroll
    for (int j = 0; j < 5; ++j) outwp[j] = mkv2(outW[2 * j], outW[2 * j + 1]);
    const float outb0 = outb[0];

    // Initial decoder state: encoder finals padded 4 -> 10 with zeros
    v2f dh0p[5], dh1p[5];
    dh0p[0] = h0f[0]; dh0p[1] = h0f[1];
    dh1p[0] = h1p[0]; dh1p[1] = h1p[1];
#pragma unroll
    for (int j = 2; j < 5; ++j) { dh0p[j] = mkv2(0.f, 0.f); dh1p[j] = mkv2(0.f, 0.f); }
    float dc0 = (u < 4) ? c0all : 0.f;
    float dc1 = (u < 4) ? c1all : 0.f;

    float my_noise = 0.f;

#pragma unroll 1
    for (int t = 0; t < T_N; ++t) {
        const float inp = dh1p[0].x;

        // L1 partial from previous h1 (independent of the L0 chain)
        v2f p1a = pk_fma(whh1a[0], dh1p[0], mkv2(b1a, 0.f));
        v2f p1b = pk_fma(whh1b[0], dh1p[0], mkv2(b1b, 0.f));
#pragma unroll
        for (int j = 1; j < 5; ++j) {
            p1a = pk_fma(whh1a[j], dh1p[j], p1a);
            p1b = pk_fma(whh1b[j], dh1p[j], p1b);
        }

        // L0 gates (2 per lane)
        v2f ga = pk_fma(whh0a[0], dh0p[0], mkv2(fmaf(wih0a, inp, b0a), 0.f));
        v2f gb = pk_fma(whh0b[0], dh0p[0], mkv2(fmaf(wih0b, inp, b0b), 0.f));
#pragma unroll
        for (int j = 1; j < 5; ++j) {
            ga = pk_fma(whh0a[j], dh0p[j], ga);
            gb = pk_fma(whh0b[j], dh0p[j], gb);
        }
        float a0 = act_ab(ga.x + ga.y, A0v, B0v);  // row0: sig(i), row1: tanh(g)
        float a1 = sig_acc(gb.x + gb.y);           // row0: sig(f), row1: sig(o)
        float iv, gvv, fv, ov;
        pl16(a0, iv, gvv);                         // iv = sig(i), gvv = tanh(g), all lanes
        pl16(a1, fv, ov);                          // fv = sig(f), ov = sig(o)
        dc0 = fmaf(fv, dc0, iv * gvv);             // all 32 lanes (rows redundant)
        const float h0u = ov * tanh_nat(dc0);
        dh0p[0].x = dppf<0x150>(h0u); dh0p[0].y = dppf<0x151>(h0u);
        dh0p[1].x = dppf<0x152>(h0u); dh0p[1].y = dppf<0x153>(h0u);
        dh0p[2].x = dppf<0x154>(h0u); dh0p[2].y = dppf<0x155>(h0u);
        dh0p[3].x = dppf<0x156>(h0u); dh0p[3].y = dppf<0x157>(h0u);
        dh0p[4].x = dppf<0x158>(h0u); dh0p[4].y = dppf<0x159>(h0u);

        // L1 gates: accumulate the post-broadcast half into p1
#pragma unroll
        for (int j = 0; j < 5; ++j) {
            p1a = pk_fma(wih1a[j], dh0p[j], p1a);
            p1b = pk_fma(wih1b[j], dh0p[j], p1b);
        }
        a0 = act_ab(p1a.x + p1a.y, A0v, B0v);
        a1 = sig_acc(p1b.x + p1b.y);
        pl16(a0, iv, gvv);
        pl16(a1, fv, ov);
        dc1 = fmaf(fv, dc1, iv * gvv);
        const float h1u = ov * tanh_nat(dc1);
        dh1p[0].x = dppf<0x150>(h1u); dh1p[0].y = dppf<0x151>(h1u);
        dh1p[1].x = dppf<0x152>(h1u); dh1p[1].y = dppf<0x153>(h1u);
        dh1p[2].x = dppf<0x154>(h1u); dh1p[2].y = dppf<0x155>(h1u);
        dh1p[3].x = dppf<0x156>(h1u); dh1p[3].y = dppf<0x157>(h1u);
        dh1p[4].x = dppf<0x158>(h1u); dh1p[4].y = dppf<0x159>(h1u);

        // noise_t = dec_out . out_W + out_b (uniform on all 32 lanes)
        v2f na = pk_fma(outwp[0], dh1p[0], mkv2(outb0, 0.f));
#pragma unroll
        for (int j = 1; j < 5; ++j) na = pk_fma(outwp[j], dh1p[j], na);
        const float nz = na.x + na.y;

        // lane l keeps t with t%32==l; flush coalesced every 32 steps
        my_noise = ((t & 31) == l) ? nz : my_noise;
        if ((t & 31) == 31) {
            const int idx = b * T_N + (t - 31) + l;
            out[NOISE_OFF + idx] = my_noise;
            float2 fin;
            fin.x = my_noise + fw0;
            fin.y = my_noise + fw1;
            ((float2*)out)[idx] = fin;
        }
    }
}

extern "C" void kernel_launch(void* const* d_in, const int* in_sizes, int n_in,
                              void* d_out, int out_size, void* d_ws, size_t ws_size,
                              hipStream_t stream) {
    const float* x     = (const float*)d_in[0];
    // d_in[1] = context (unused by the reference)
    const float* eWih0 = (const float*)d_in[2];
    const float* eWhh0 = (const float*)d_in[3];
    const float* ebih0 = (const float*)d_in[4];
    const float* ebhh0 = (const float*)d_in[5];
    const float* eWih1 = (const float*)d_in[6];
    const float* eWhh1 = (const float*)d_in[7];
    const float* ebih1 = (const float*)d_in[8];
    const float* ebhh1 = (const float*)d_in[9];
    const float* dWih0 = (const float*)d_in[10];
    const float* dWhh0 = (const float*)d_in[11];
    const float* dbih0 = (const float*)d_in[12];
    const float* dbhh0 = (const float*)d_in[13];
    const float* dWih1 = (const float*)d_in[14];
    const float* dWhh1 = (const float*)d_in[15];
    const float* dbih1 = (const float*)d_in[16];
    const float* dbhh1 = (const float*)d_in[17];
    const float* fcW   = (const float*)d_in[18];
    const float* fcb   = (const float*)d_in[19];
    const float* outW  = (const float*)d_in[20];
    const float* outb  = (const float*)d_in[21];

    float* out = (float*)d_out;

    // 4096 elems x 32 lanes = 131072 threads = 2048 waves = 2 waves/SIMD
    fused_kernel<<<dim3((B_N * 32) / 256), dim3(256), 0, stream>>>(
        x, eWih0, eWhh0, ebih0, ebhh0, eWih1, eWhh1, ebih1, ebhh1,
        dWih0, dWhh0, dbih0, dbhh0, dWih1, dWhh1, dbih1, dbhh1,
        fcW, fcb, outW, outb, out);
}

// Round 13
// 360.696 us; speedup vs baseline: 1.2600x; 1.2600x over previous
//
#include <hip/hip_runtime.h>

// Problem constants
#define B_N 4096
#define T_N 512
// Output layout (floats): final (B,T,2) | fwd_out (B,2) | noise (B,T,1)
#define FWD_OFF   (B_N * T_N * 2)        // 4194304
#define NOISE_OFF (FWD_OFF + B_N * 2)    // 4202496

#define S_SIG  (-1.4426950408889634f)   // -log2(e)
#define S_TANH (-2.8853900817779268f)   // -2*log2(e)

typedef float v2f __attribute__((ext_vector_type(2)));
__device__ __forceinline__ v2f mkv2(float a, float b) { v2f r; r.x = a; r.y = b; return r; }

// native packed math: clang selects v_pk_fma_f32 / v_pk_mul_f32 (gfx90a+)
__device__ __forceinline__ v2f pk_fma(v2f a, v2f b, v2f c) { return a * b + c; }

// act on pre-scaled accumulator: returns fma(A, rcp(1+exp2(a)), B)
// A=1,B=0  -> sigmoid(v) where a = -log2e*v
// A=2,B=-1 -> tanh(v)    where a = -2log2e*v
__device__ __forceinline__ float act_ab(float a, float A, float Bc) {
    float r = __builtin_amdgcn_rcpf(1.0f + __builtin_amdgcn_exp2f(a));
    return fmaf(A, r, Bc);
}
__device__ __forceinline__ float sig_acc(float a) {
    return __builtin_amdgcn_rcpf(1.0f + __builtin_amdgcn_exp2f(a));
}
__device__ __forceinline__ float tanh_acc(float a) {
    return fmaf(2.0f, __builtin_amdgcn_rcpf(1.0f + __builtin_amdgcn_exp2f(a)), -1.0f);
}
__device__ __forceinline__ float tanh_nat(float v) {
    return tanh_acc(v * S_TANH);
}

// ---- DPP cross-lane (all-VALU, zero DS in the kernel) ----
// ROW_ROR:N (0x120+N): dst lane i <- src lane (i-N)&15 within each 16-lane row
// ROW_NEWBCAST:J (0x150+J, gfx90a+): dst lane i <- src lane J of its 16-lane row
template<int CTRL>
__device__ __forceinline__ float dppf(float v) {
    return __int_as_float(__builtin_amdgcn_update_dpp(
        __float_as_int(v), __float_as_int(v), CTRL, 0xF, 0xF, false));
}

// FINAL (round-13 = round-10 revert, best measured: 293.4 us steady):
// 16 lanes/elem, 4 elems/wave, 1 wave/SIMD, zero DS, DPP cross-lane,
// native packed v2f dots. The layout trade-off map (r3/r10/r12) shows
// instruction amortization (4 elems per wave-instruction) beats occupancy
// at every point; residual ~24% idle is LSTM act-chain latency, unfixable
// by placement (r11), restructure (r8/r9), or TLP relayouts (r3/r12).
__global__ __attribute__((amdgpu_waves_per_eu(1, 1))) __launch_bounds__(256)
void fused_kernel(
    const float* __restrict__ x,
    const float* __restrict__ eWih0, const float* __restrict__ eWhh0,
    const float* __restrict__ ebih0, const float* __restrict__ ebhh0,
    const float* __restrict__ eWih1, const float* __restrict__ eWhh1,
    const float* __restrict__ ebih1, const float* __restrict__ ebhh1,
    const float* __restrict__ dWih0, const float* __restrict__ dWhh0,
    const float* __restrict__ dbih0, const float* __restrict__ dbhh0,
    const float* __restrict__ dWih1, const float* __restrict__ dWhh1,
    const float* __restrict__ dbih1, const float* __restrict__ dbhh1,
    const float* __restrict__ fcW, const float* __restrict__ fcb,
    const float* __restrict__ outW, const float* __restrict__ outb,
    float* __restrict__ out)
{
    const int tid  = blockIdx.x * 256 + threadIdx.x;
    const int b    = tid >> 4;     // batch element
    const int lane = tid & 15;     // 16 lanes per element (= one DPP row)

    // =================== ENCODER: gate-row-parallel (H=4) ===================
    const int kk = lane >> 2;
    const float sc = (kk == 2) ? S_TANH : S_SIG;
    const float Ak = (kk == 2) ? 2.0f : 1.0f;
    const float Bk = (kk == 2) ? -1.0f : 0.0f;

    v2f h0p[2] = {mkv2(0.f, 0.f), mkv2(0.f, 0.f)};
    v2f h1p[2] = {mkv2(0.f, 0.f), mkv2(0.f, 0.f)};
    float c0 = 0.f, c1 = 0.f;
    float fw0, fw1;

    {
        const int r = lane;
        float ew0 = eWih0[r] * sc;
        float eb0 = (ebih0[r] + ebhh0[r]) * sc;
        float eb1 = (ebih1[r] + ebhh1[r]) * sc;
        v2f ewh0p[2], ewi1p[2], ewh1p[2];
#pragma unroll
        for (int j = 0; j < 2; ++j) {
            ewh0p[j] = mkv2(eWhh0[r * 4 + 2 * j], eWhh0[r * 4 + 2 * j + 1]) * sc;
            ewi1p[j] = mkv2(eWih1[r * 4 + 2 * j], eWih1[r * 4 + 2 * j + 1]) * sc;
            ewh1p[j] = mkv2(eWhh1[r * 4 + 2 * j], eWhh1[r * 4 + 2 * j + 1]) * sc;
        }

        const float4* __restrict__ xq4 = (const float4*)(x + (long)b * T_N);
        float4 xq = xq4[0];

        auto estep = [&](float xc) {
            // L1 partial from previous h1 (independent of L0 chain)
            v2f pp = pk_fma(ewh1p[0], h1p[0], mkv2(eb1, 0.f));
            pp = pk_fma(ewh1p[1], h1p[1], pp);

            // L0 gate-row dot
            v2f gg = pk_fma(ewh0p[0], h0p[0], mkv2(fmaf(ew0, xc, eb0), 0.f));
            gg = pk_fma(ewh0p[1], h0p[1], gg);
            float gate = act_ab(gg.x + gg.y, Ak, Bk);
            // gate combine via DPP row rotate (src lane = (i-N)&15):
            // on lanes 0..3: ror:12 -> i+4 (f), ror:8 -> i+8 (g), ror:4 -> i+12 (o)
            float fv = dppf<0x12C>(gate);
            float gv = dppf<0x128>(gate);
            float ov = dppf<0x124>(gate);
            c0 = fmaf(fv, c0, gate * gv);     // valid on lanes 0..3 (gate = i there)
            float h0u = ov * tanh_nat(c0);
            h0p[0].x = dppf<0x150>(h0u); h0p[0].y = dppf<0x151>(h0u);
            h0p[1].x = dppf<0x152>(h0u); h0p[1].y = dppf<0x153>(h0u);

            // L1 gate-row dot (post-broadcast half)
            v2f qq = pk_fma(ewi1p[0], h0p[0], pp);
            qq = pk_fma(ewi1p[1], h0p[1], qq);
            float gate1 = act_ab(qq.x + qq.y, Ak, Bk);
            fv = dppf<0x12C>(gate1);
            gv = dppf<0x128>(gate1);
            ov = dppf<0x124>(gate1);
            c1 = fmaf(fv, c1, gate1 * gv);
            float h1u = ov * tanh_nat(c1);
            h1p[0].x = dppf<0x150>(h1u); h1p[0].y = dppf<0x151>(h1u);
            h1p[1].x = dppf<0x152>(h1u); h1p[1].y = dppf<0x153>(h1u);
        };

        for (int tb = 0; tb < T_N / 4; ++tb) {
            float4 xn = (tb + 1 < T_N / 4) ? xq4[tb + 1] : xq;  // prefetch
            estep(xq.x); estep(xq.y); estep(xq.z); estep(xq.w);
            xq = xn;
        }

        // fwd_out = h1 @ fc_W.T + fc_b   (computed uniformly on all lanes)
        fw0 = fcb[0];
        fw1 = fcb[1];
        fw0 = fmaf(fcW[0], h1p[0].x, fw0); fw0 = fmaf(fcW[1], h1p[0].y, fw0);
        fw0 = fmaf(fcW[2], h1p[1].x, fw0); fw0 = fmaf(fcW[3], h1p[1].y, fw0);
        fw1 = fmaf(fcW[4], h1p[0].x, fw1); fw1 = fmaf(fcW[5], h1p[0].y, fw1);
        fw1 = fmaf(fcW[6], h1p[1].x, fw1); fw1 = fmaf(fcW[7], h1p[1].y, fw1);
        if (lane == 0) {
            out[FWD_OFF + b * 2 + 0] = fw0;
            out[FWD_OFF + b * 2 + 1] = fw1;
        }
    }

    // =================== DECODER: unit-parallel (H=10) ===================
    // lane = unit (0..9 active; 10..15 shadow 9). All dots packed as v2f.
    const int uc = (lane < 10) ? lane : 9;

    float wih0r[4], b0r[4], b1r[4];
    v2f whh0p[4][5], wih1p[4][5], whh1p[4][5];
#pragma unroll
    for (int k = 0; k < 4; ++k) {
        const int r = k * 10 + uc;
        const float sck = (k == 2) ? S_TANH : S_SIG;
        wih0r[k] = dWih0[r] * sck;
        b0r[k] = (dbih0[r] + dbhh0[r]) * sck;
        b1r[k] = (dbih1[r] + dbhh1[r]) * sck;
#pragma unroll
        for (int j = 0; j < 5; ++j) {
            whh0p[k][j] = mkv2(dWhh0[r * 10 + 2 * j], dWhh0[r * 10 + 2 * j + 1]) * sck;
            wih1p[k][j] = mkv2(dWih1[r * 10 + 2 * j], dWih1[r * 10 + 2 * j + 1]) * sck;
            whh1p[k][j] = mkv2(dWhh1[r * 10 + 2 * j], dWhh1[r * 10 + 2 * j + 1]) * sck;
        }
    }
    v2f outwp[5];
#pragma unroll
    for (int j = 0; j < 5; ++j) outwp[j] = mkv2(outW[2 * j], outW[2 * j + 1]);
    const float outb0 = outb[0];

    // Initial decoder state: encoder finals padded 4 -> 10 with zeros
    v2f dh0p[5], dh1p[5];
    dh0p[0] = h0p[0]; dh0p[1] = h0p[1];
    dh1p[0] = h1p[0]; dh1p[1] = h1p[1];
#pragma unroll
    for (int j = 2; j < 5; ++j) { dh0p[j] = mkv2(0.f, 0.f); dh1p[j] = mkv2(0.f, 0.f); }
    float dc0 = (lane < 4) ? c0 : 0.f;
    float dc1 = (lane < 4) ? c1 : 0.f;

    float my_noise = 0.f;

    for (int t = 0; t < T_N; ++t) {
        const float inp = dh1p[0].x;

        // L1 partial from previous h1 (independent of L0 chain)
        v2f p1[4];
#pragma unroll
        for (int k = 0; k < 4; ++k) {
            p1[k] = pk_fma(whh1p[k][0], dh1p[0], mkv2(b1r[k], 0.f));
#pragma unroll
            for (int j = 1; j < 5; ++j) p1[k] = pk_fma(whh1p[k][j], dh1p[j], p1[k]);
        }

        // L0 gates
        v2f g2[4];
#pragma unroll
        for (int k = 0; k < 4; ++k) {
            g2[k] = pk_fma(whh0p[k][0], dh0p[0], mkv2(fmaf(wih0r[k], inp, b0r[k]), 0.f));
#pragma unroll
            for (int j = 1; j < 5; ++j) g2[k] = pk_fma(whh0p[k][j], dh0p[j], g2[k]);
        }
        float iv = sig_acc(g2[0].x + g2[0].y);
        float fv = sig_acc(g2[1].x + g2[1].y);
        float gv = tanh_acc(g2[2].x + g2[2].y);
        float ov = sig_acc(g2[3].x + g2[3].y);
        dc0 = fmaf(fv, dc0, iv * gv);
        const float h0u = ov * tanh_nat(dc0);
        dh0p[0].x = dppf<0x150>(h0u); dh0p[0].y = dppf<0x151>(h0u);
        dh0p[1].x = dppf<0x152>(h0u); dh0p[1].y = dppf<0x153>(h0u);
        dh0p[2].x = dppf<0x154>(h0u); dh0p[2].y = dppf<0x155>(h0u);
        dh0p[3].x = dppf<0x156>(h0u); dh0p[3].y = dppf<0x157>(h0u);
        dh0p[4].x = dppf<0x158>(h0u); dh0p[4].y = dppf<0x159>(h0u);

        // L1 gates: accumulate the post-broadcast half into p1
#pragma unroll
        for (int k = 0; k < 4; ++k) {
#pragma unroll
            for (int j = 0; j < 5; ++j) p1[k] = pk_fma(wih1p[k][j], dh0p[j], p1[k]);
        }
        iv = sig_acc(p1[0].x + p1[0].y);
        fv = sig_acc(p1[1].x + p1[1].y);
        gv = tanh_acc(p1[2].x + p1[2].y);
        ov = sig_acc(p1[3].x + p1[3].y);
        dc1 = fmaf(fv, dc1, iv * gv);
        const float h1u = ov * tanh_nat(dc1);
        dh1p[0].x = dppf<0x150>(h1u); dh1p[0].y = dppf<0x151>(h1u);
        dh1p[1].x = dppf<0x152>(h1u); dh1p[1].y = dppf<0x153>(h1u);
        dh1p[2].x = dppf<0x154>(h1u); dh1p[2].y = dppf<0x155>(h1u);
        dh1p[3].x = dppf<0x156>(h1u); dh1p[3].y = dppf<0x157>(h1u);
        dh1p[4].x = dppf<0x158>(h1u); dh1p[4].y = dppf<0x159>(h1u);

        // noise_t = dec_out . out_W + out_b (uniform on all 16 lanes)
        v2f na = pk_fma(outwp[0], dh1p[0], mkv2(outb0, 0.f));
#pragma unroll
        for (int j = 1; j < 5; ++j) na = pk_fma(outwp[j], dh1p[j], na);
        const float nz = na.x + na.y;

        // lane u keeps t with t%16==u; flush coalesced every 16 steps
        my_noise = ((t & 15) == lane) ? nz : my_noise;
        if ((t & 15) == 15) {
            const int idx = b * T_N + (t - 15) + lane;
            out[NOISE_OFF + idx] = my_noise;
            float2 fin;
            fin.x = my_noise + fw0;
            fin.y = my_noise + fw1;
            ((float2*)out)[idx] = fin;
        }
    }
}

extern "C" void kernel_launch(void* const* d_in, const int* in_sizes, int n_in,
                              void* d_out, int out_size, void* d_ws, size_t ws_size,
                              hipStream_t stream) {
    const float* x     = (const float*)d_in[0];
    // d_in[1] = context (unused by the reference)
    const float* eWih0 = (const float*)d_in[2];
    const float* eWhh0 = (const float*)d_in[3];
    const float* ebih0 = (const float*)d_in[4];
    const float* ebhh0 = (const float*)d_in[5];
    const float* eWih1 = (const float*)d_in[6];
    const float* eWhh1 = (const float*)d_in[7];
    const float* ebih1 = (const float*)d_in[8];
    const float* ebhh1 = (const float*)d_in[9];
    const float* dWih0 = (const float*)d_in[10];
    const float* dWhh0 = (const float*)d_in[11];
    const float* dbih0 = (const float*)d_in[12];
    const float* dbhh0 = (const float*)d_in[13];
    const float* dWih1 = (const float*)d_in[14];
    const float* dWhh1 = (const float*)d_in[15];
    const float* dbih1 = (const float*)d_in[16];
    const float* dbhh1 = (const float*)d_in[17];
    const float* fcW   = (const float*)d_in[18];
    const float* fcb   = (const float*)d_in[19];
    const float* outW  = (const float*)d_in[20];
    const float* outb  = (const float*)d_in[21];

    float* out = (float*)d_out;

    // 4096 elems x 16 lanes = 65536 threads = 1024 waves = 1 wave/SIMD
    fused_kernel<<<dim3((B_N * 16) / 256), dim3(256), 0, stream>>>(
        x, eWih0, eWhh0, ebih0, ebhh0, eWih1, eWhh1, ebih1, ebhh1,
        dWih0, dWhh0, dbih0, dbhh0, dWih1, dWhh1, dbih1, dbhh1,
        fcW, fcb, outW, outb, out);
}